// Round 4
// baseline (444.948 us; speedup 1.0000x reference)
//
#include <hip/hip_runtime.h>
#include <hip/hip_bf16.h>

// Haar wavelet transform: x (B=16, C=64, H=512, W=512) f32 ->
// 4 outputs (LL, LH, HL, HH), each (16, 64, 256, 256) f32, concatenated in d_out.
//
// R4: exploit index structure — with 2^19 threads and W4*HO = 2^14 work units
// per 16 channels, the per-iteration stride moves ONLY the channel index
// (bc += 32). Decompose tid once; loop body = 4 loads + butterfly + 4 stores
// + constant pointer bumps. __launch_bounds__(256,8) pins VGPR<=64 so we get
// 32 waves/CU (max occupancy) for HBM latency hiding.

#define B_ 16
#define C_ 64
#define H_ 512
#define W_ 512
#define HO (H_/2)
#define WO (W_/2)
#define NPLANE (B_*C_*HO*WO)          // 67,108,864 elements per output plane
#define NITER 32                      // exact: 16,777,216 work / 524,288 threads

typedef float f32x4 __attribute__((ext_vector_type(4)));

__global__ __launch_bounds__(256, 8) void haar_kernel(const float* __restrict__ x,
                                                      float* __restrict__ out) {
    const int tid = blockIdx.x * 256 + threadIdx.x;   // 0..524287
    const int w4  = tid & 63;                          // float4 index in output row
    const int h   = (tid >> 6) & 255;                  // output row
    const int bc0 = tid >> 14;                         // 0..31 starting channel

    const float* in_ptr = x   + (size_t)bc0 * (H_ * W_) + (size_t)(2 * h) * W_ + 8 * w4;
    float*      out_ptr = out + (size_t)bc0 * (HO * WO) + (size_t)h * WO + 4 * w4;

#pragma unroll 2
    for (int it = 0; it < NITER; ++it) {
        const f32x4 r0a = *reinterpret_cast<const f32x4*>(in_ptr);
        const f32x4 r0b = *reinterpret_cast<const f32x4*>(in_ptr + 4);
        const f32x4 r1a = *reinterpret_cast<const f32x4*>(in_ptr + W_);
        const f32x4 r1b = *reinterpret_cast<const f32x4*>(in_ptr + W_ + 4);

        f32x4 ll, lh, hl, hh;
        {   // column pair 0: (r0a[0],r0a[1] | r1a[0],r1a[1])
            const float p = r0a[0] + r0a[1], q = r0a[0] - r0a[1];
            const float r = r1a[0] + r1a[1], s = r1a[0] - r1a[1];
            ll[0] = (p + r) * 0.5f; hl[0] = (p - r) * 0.5f;
            lh[0] = (q + s) * 0.5f; hh[0] = (q - s) * 0.5f;
        }
        {   // column pair 1
            const float p = r0a[2] + r0a[3], q = r0a[2] - r0a[3];
            const float r = r1a[2] + r1a[3], s = r1a[2] - r1a[3];
            ll[1] = (p + r) * 0.5f; hl[1] = (p - r) * 0.5f;
            lh[1] = (q + s) * 0.5f; hh[1] = (q - s) * 0.5f;
        }
        {   // column pair 2
            const float p = r0b[0] + r0b[1], q = r0b[0] - r0b[1];
            const float r = r1b[0] + r1b[1], s = r1b[0] - r1b[1];
            ll[2] = (p + r) * 0.5f; hl[2] = (p - r) * 0.5f;
            lh[2] = (q + s) * 0.5f; hh[2] = (q - s) * 0.5f;
        }
        {   // column pair 3
            const float p = r0b[2] + r0b[3], q = r0b[2] - r0b[3];
            const float r = r1b[2] + r1b[3], s = r1b[2] - r1b[3];
            ll[3] = (p + r) * 0.5f; hl[3] = (p - r) * 0.5f;
            lh[3] = (q + s) * 0.5f; hh[3] = (q - s) * 0.5f;
        }

        __builtin_nontemporal_store(ll, reinterpret_cast<f32x4*>(out_ptr));
        __builtin_nontemporal_store(lh, reinterpret_cast<f32x4*>(out_ptr + 1LL * NPLANE));
        __builtin_nontemporal_store(hl, reinterpret_cast<f32x4*>(out_ptr + 2LL * NPLANE));
        __builtin_nontemporal_store(hh, reinterpret_cast<f32x4*>(out_ptr + 3LL * NPLANE));

        in_ptr  += 32LL * H_ * W_;    // +32 channels
        out_ptr += 32LL * HO * WO;
    }
}

extern "C" void kernel_launch(void* const* d_in, const int* in_sizes, int n_in,
                              void* d_out, int out_size, void* d_ws, size_t ws_size,
                              hipStream_t stream) {
    const float* x = (const float*)d_in[0];
    float* out = (float*)d_out;
    haar_kernel<<<2048, 256, 0, stream>>>(x, out);
}

// Round 5
// 430.868 us; speedup vs baseline: 1.0327x; 1.0327x over previous
//
#include <hip/hip_runtime.h>
#include <hip/hip_bf16.h>

// Haar wavelet transform: x (B=16, C=64, H=512, W=512) f32 ->
// 4 outputs (LL, LH, HL, HH), each (16, 64, 256, 256) f32, concatenated in d_out.
//
// R5: identical to R3 (best: 430us) EXCEPT plain stores instead of
// __builtin_nontemporal_store. Theory: NT bypasses L2 write-combining ->
// sub-granule (16B) writes hit HBM3E ECC read-modify-write -> write BW loss.
// Plain stores let L2 assemble full lines (fill kernel at 6.5 TB/s proves
// that path is fast). Single-variable A/B vs R3.

#define B_ 16
#define C_ 64
#define H_ 512
#define W_ 512
#define HO (H_/2)
#define WO (W_/2)
#define NPLANE (B_*C_*HO*WO)          // 67,108,864 elements per output plane
#define W4 (WO/4)                     // 64 float4 per output row
#define NWORK (B_*C_*HO*W4)           // 16,777,216 work units
#define NTHREADS (2048*256)           // 524,288
#define NITER (NWORK/NTHREADS)        // 32, exact

typedef float f32x4 __attribute__((ext_vector_type(4)));

__global__ __launch_bounds__(256) void haar_kernel(const float* __restrict__ x,
                                                   float* __restrict__ out) {
    const int tid = blockIdx.x * 256 + threadIdx.x;   // 0..524287
#pragma unroll 4
    for (int it = 0; it < NITER; ++it) {
        const long long idx = (long long)tid + (long long)it * NTHREADS;
        // decompose: idx -> (bc, h, w4)
        const int w4 = (int)(idx & (W4 - 1));         // 0..63
        const long long rest = idx >> 6;
        const int h = (int)(rest & (HO - 1));         // 0..255
        const long long bc = rest >> 8;               // 0..1023

        const long long in_base = bc * (long long)(H_ * W_) + (long long)(2 * h) * W_ + 8 * w4;
        // 4 independent 16B loads: rows 2h, 2h+1, two adjacent float4 each
        const f32x4 r0a = *reinterpret_cast<const f32x4*>(x + in_base);
        const f32x4 r0b = *reinterpret_cast<const f32x4*>(x + in_base + 4);
        const f32x4 r1a = *reinterpret_cast<const f32x4*>(x + in_base + W_);
        const f32x4 r1b = *reinterpret_cast<const f32x4*>(x + in_base + W_ + 4);

        // pairs: (a,b) adjacent in row0, (c,d) adjacent in row1
        f32x4 ll, lh, hl, hh;
        ll[0] = (r0a[0] + r0a[1] + r1a[0] + r1a[1]) * 0.5f;
        ll[1] = (r0a[2] + r0a[3] + r1a[2] + r1a[3]) * 0.5f;
        ll[2] = (r0b[0] + r0b[1] + r1b[0] + r1b[1]) * 0.5f;
        ll[3] = (r0b[2] + r0b[3] + r1b[2] + r1b[3]) * 0.5f;

        lh[0] = (r0a[0] - r0a[1] + r1a[0] - r1a[1]) * 0.5f;
        lh[1] = (r0a[2] - r0a[3] + r1a[2] - r1a[3]) * 0.5f;
        lh[2] = (r0b[0] - r0b[1] + r1b[0] - r1b[1]) * 0.5f;
        lh[3] = (r0b[2] - r0b[3] + r1b[2] - r1b[3]) * 0.5f;

        hl[0] = (r0a[0] + r0a[1] - r1a[0] - r1a[1]) * 0.5f;
        hl[1] = (r0a[2] + r0a[3] - r1a[2] - r1a[3]) * 0.5f;
        hl[2] = (r0b[0] + r0b[1] - r1b[0] - r1b[1]) * 0.5f;
        hl[3] = (r0b[2] + r0b[3] - r1b[2] - r1b[3]) * 0.5f;

        hh[0] = (r0a[0] - r0a[1] - r1a[0] + r1a[1]) * 0.5f;
        hh[1] = (r0a[2] - r0a[3] - r1a[2] + r1a[3]) * 0.5f;
        hh[2] = (r0b[0] - r0b[1] - r1b[0] + r1b[1]) * 0.5f;
        hh[3] = (r0b[2] - r0b[3] - r1b[2] + r1b[3]) * 0.5f;

        const long long out_base = bc * (long long)(HO * WO) + (long long)h * WO + 4 * w4;
        *reinterpret_cast<f32x4*>(out + out_base)               = ll;
        *reinterpret_cast<f32x4*>(out + out_base + 1LL*NPLANE)  = lh;
        *reinterpret_cast<f32x4*>(out + out_base + 2LL*NPLANE)  = hl;
        *reinterpret_cast<f32x4*>(out + out_base + 3LL*NPLANE)  = hh;
    }
}

extern "C" void kernel_launch(void* const* d_in, const int* in_sizes, int n_in,
                              void* d_out, int out_size, void* d_ws, size_t ws_size,
                              hipStream_t stream) {
    const float* x = (const float*)d_in[0];
    float* out = (float*)d_out;
    haar_kernel<<<2048, 256, 0, stream>>>(x, out);
}

// Round 6
// 421.385 us; speedup vs baseline: 1.0559x; 1.0225x over previous
//
#include <hip/hip_runtime.h>
#include <hip/hip_bf16.h>

// Haar wavelet transform: x (B=16, C=64, H=512, W=512) f32 ->
// 4 outputs (LL, LH, HL, HH), each (16, 64, 256, 256) f32, concatenated.
//
// R6: LDS-repack so each WAVE writes ONE plane as a 4KB contiguous stream.
// Theory: planes are 256MB apart (same DRAM channel/bank bits) -> a wave's
// four interleaved 1KB plane-writes serialize on same-bank row activates.
// Block (4 waves) processes a tile = 4 output rows x 256 cols x 4 planes:
//   Phase A: wave w loads input row pair (2h+2w, 2h+2w+1) with DENSE 16B
//            loads, computes the butterfly, stores float2s to LDS.
//   Phase B: wave w writes plane w: 4 rows x 1KB = 4KB contiguous, row order
//            rotated by wave so concurrent waves hit different offsets.

#define B_ 16
#define C_ 64
#define H_ 512
#define W_ 512
#define HO (H_/2)
#define WO (W_/2)
#define NPLANE (B_*C_*HO*WO)     // 67,108,864 elements per plane
#define NITER 32                 // 65536 tiles / 2048 blocks

typedef float f32x4 __attribute__((ext_vector_type(4)));
typedef float f32x2 __attribute__((ext_vector_type(2)));

__global__ __launch_bounds__(256) void haar_kernel(const float* __restrict__ x,
                                                   float* __restrict__ out) {
    __shared__ float lds[4][4][256];     // [out_row_in_tile][plane][col]
    const int w    = threadIdx.x >> 6;   // wave id 0..3
    const int lane = threadIdx.x & 63;

    for (int j = 0; j < NITER; ++j) {
        const int t  = j * 2048 + (int)blockIdx.x;   // tile id, device-sweep order
        const int bc = t >> 6;                       // channel 0..1023
        const int h4 = t & 63;                       // tile row group 0..63

        // ---- Phase A: dense loads + butterfly -> LDS ----
        const float* in_row = x + (size_t)bc * (H_ * W_)
                                + (size_t)(h4 * 8 + 2 * w) * W_ + 4 * lane;
        const f32x4 r0a = *reinterpret_cast<const f32x4*>(in_row);            // cols 4i..4i+3
        const f32x4 r0b = *reinterpret_cast<const f32x4*>(in_row + 256);      // cols 256+4i..
        const f32x4 r1a = *reinterpret_cast<const f32x4*>(in_row + W_);
        const f32x4 r1b = *reinterpret_cast<const f32x4*>(in_row + W_ + 256);

        f32x2 ll_a, lh_a, hl_a, hh_a, ll_b, lh_b, hl_b, hh_b;
        {   // first half: out cols 2i, 2i+1
            float p0 = r0a[0] + r0a[1], q0 = r0a[0] - r0a[1];
            float r0 = r1a[0] + r1a[1], s0 = r1a[0] - r1a[1];
            ll_a[0] = (p0 + r0) * 0.5f; hl_a[0] = (p0 - r0) * 0.5f;
            lh_a[0] = (q0 + s0) * 0.5f; hh_a[0] = (q0 - s0) * 0.5f;
            float p1 = r0a[2] + r0a[3], q1 = r0a[2] - r0a[3];
            float r1 = r1a[2] + r1a[3], s1 = r1a[2] - r1a[3];
            ll_a[1] = (p1 + r1) * 0.5f; hl_a[1] = (p1 - r1) * 0.5f;
            lh_a[1] = (q1 + s1) * 0.5f; hh_a[1] = (q1 - s1) * 0.5f;
        }
        {   // second half: out cols 128+2i, 128+2i+1
            float p0 = r0b[0] + r0b[1], q0 = r0b[0] - r0b[1];
            float r0 = r1b[0] + r1b[1], s0 = r1b[0] - r1b[1];
            ll_b[0] = (p0 + r0) * 0.5f; hl_b[0] = (p0 - r0) * 0.5f;
            lh_b[0] = (q0 + s0) * 0.5f; hh_b[0] = (q0 - s0) * 0.5f;
            float p1 = r0b[2] + r0b[3], q1 = r0b[2] - r0b[3];
            float r1 = r1b[2] + r1b[3], s1 = r1b[2] - r1b[3];
            ll_b[1] = (p1 + r1) * 0.5f; hl_b[1] = (p1 - r1) * 0.5f;
            lh_b[1] = (q1 + s1) * 0.5f; hh_b[1] = (q1 - s1) * 0.5f;
        }

        *reinterpret_cast<f32x2*>(&lds[w][0][2 * lane])       = ll_a;
        *reinterpret_cast<f32x2*>(&lds[w][0][128 + 2 * lane]) = ll_b;
        *reinterpret_cast<f32x2*>(&lds[w][1][2 * lane])       = lh_a;
        *reinterpret_cast<f32x2*>(&lds[w][1][128 + 2 * lane]) = lh_b;
        *reinterpret_cast<f32x2*>(&lds[w][2][2 * lane])       = hl_a;
        *reinterpret_cast<f32x2*>(&lds[w][2][128 + 2 * lane]) = hl_b;
        *reinterpret_cast<f32x2*>(&lds[w][3][2 * lane])       = hh_a;
        *reinterpret_cast<f32x2*>(&lds[w][3][128 + 2 * lane]) = hh_b;

        __syncthreads();

        // ---- Phase B: wave w writes plane w, 4KB contiguous, rotated rows ----
        float* plane_base = out + (size_t)w * NPLANE + (size_t)bc * (HO * WO)
                                + (size_t)(h4 * 4) * WO + 4 * lane;
#pragma unroll
        for (int s = 0; s < 4; ++s) {
            const int r = (w + s) & 3;
            const f32x4 v = *reinterpret_cast<const f32x4*>(&lds[r][w][4 * lane]);
            *reinterpret_cast<f32x4*>(plane_base + (size_t)r * WO) = v;
        }

        __syncthreads();   // LDS reused next iteration
    }
}

extern "C" void kernel_launch(void* const* d_in, const int* in_sizes, int n_in,
                              void* d_out, int out_size, void* d_ws, size_t ws_size,
                              hipStream_t stream) {
    const float* x = (const float*)d_in[0];
    float* out = (float*)d_out;
    haar_kernel<<<2048, 256, 0, stream>>>(x, out);
}